// Round 9
// baseline (17.138 us; speedup 1.0000x reference)
//
#include <hip/hip_runtime.h>
#include <hip/hip_bf16.h>

#define INF_SENT 1.0e6f
#define ALPHA 1.0f
#define INV_BETA 0.5f

#define B_ 16
#define H_ 256
#define W_ 256
#define SEGB 16           // rows per block
#define SUB 8             // rows per thread-half
#define NSEGB 16          // H_/SEGB
#define NBLK (B_ * NSEGB) // 256 blocks
#define RPAD 16           // vertical halo rows each side

// ---------------------------------------------------------------------------
// Fused self-sufficient kernel, 512 threads = 256 cols x 2 row-halves.
// Per (b, 16-row segment) block:
//   1) per-half vertical two-scan over its 8 rows +/- RPAD halo (exact when
//      true vertical distance <= RPAD); halo loads overlap between halves
//      (L1) and between adjacent blocks of the same batch (L2, XCD swizzle)
//   2) LDS row tiles -> adaptive exact horizontal min (early exit d^2>=best)
//   3) best >= (RPAD+1)^2 => exact global 2D search (never taken @ p=0.5;
//      preserves exactness for any input)
//   4) CE + weight -> one partial per block. No cross-block deps/atomics.
//
// XCD swizzle: blocks dispatch round-robin over 8 XCDs by blockIdx%8, so
// decode (b, ss) such that all 16 segments of a batch land on one XCD:
//   xcd = g&7, idx = g>>3, b = xcd*2 + (idx>>4), ss = idx&15.
// Purely a locality heuristic — correctness never depends on placement.
// ---------------------------------------------------------------------------
__global__ __launch_bounds__(512) void
fused_loss_kernel(const float* __restrict__ pred,
                  const int* __restrict__ mask,
                  float* __restrict__ partials) {
    const int g    = blockIdx.x;
    const int b    = ((g & 7) << 1) | ((g >> 3) >> 4);
    const int ss   = (g >> 3) & 15;
    const int tid  = threadIdx.x;
    const int j    = tid & 255;
    const int half = tid >> 8;                 // 0 or 1
    const int i0   = ss * SEGB + half * SUB;   // first owned row

    __shared__ float s_g2[SEGB][W_];
    __shared__ float s_part[8];

    // prefetch logits early; latency hides under the scans
    float pf0[SUB], pf1[SUB];
    const int pb = ((b * 2) << 16) + (i0 << 8) + j;
    #pragma unroll
    for (int r = 0; r < SUB; ++r) {
        pf0[r] = pred[pb + (r << 8)];
        pf1[r] = pred[pb + (r << 8) + H_ * W_];
    }

    const int mb = (b << 16) + j;

    // forward scan: rows i0-RPAD .. i0+SUB-1 (out-of-image -> INF)
    float F[SUB], initOwn[SUB];
    float c = INF_SENT;
    #pragma unroll
    for (int t = 0; t < RPAD + SUB; ++t) {
        const int row = i0 - RPAD + t;
        float init = INF_SENT;
        if (row >= 0 && row < H_) init = mask[mb + (row << 8)] ? 0.0f : INF_SENT;
        c = fminf(c + 1.0f, init);
        if (t >= RPAD) { F[t - RPAD] = c; initOwn[t - RPAD] = init; }
    }
    // backward scan: rows i0+SUB+RPAD-1 .. i0
    c = INF_SENT;
    #pragma unroll
    for (int t = RPAD + SUB + RPAD - 1; t >= RPAD; --t) {
        const int row = i0 - RPAD + t;
        float init;
        if (t < RPAD + SUB) init = initOwn[t - RPAD];
        else { init = INF_SENT; if (row < H_) init = mask[mb + (row << 8)] ? 0.0f : INF_SENT; }
        c = fminf(c + 1.0f, init);
        if (t < RPAD + SUB) {
            float gg = fminf(F[t - RPAD], c);
            s_g2[half * SUB + (t - RPAD)][j] = gg * gg;
        }
    }
    __syncthreads();

    // per-row adaptive exact horizontal min + CE + weight
    float vsum = 0.0f;
    #pragma unroll
    for (int r = 0; r < SUB; ++r) {
        const int lr = half * SUB + r;
        float best = s_g2[lr][j];
        for (int d = 1; d < W_; ++d) {
            float d2 = (float)(d * d);
            if (d2 >= best) break;
            int kl = j - d, kr = j + d;
            if (kl >= 0)  best = fminf(best, s_g2[lr][kl] + d2);
            if (kr < W_)  best = fminf(best, s_g2[lr][kr] + d2);
        }

        // window-truncation guard: exact global 2D search (never taken here)
        if (best >= (float)((RPAD + 1) * (RPAD + 1))) {
            const int ii = i0 + r;
            const int mrow = (b << 16);
            int bi = 1 << 28;
            for (int i2 = 0; i2 < H_; ++i2) {
                int dy = i2 - ii, dy2 = dy * dy;
                if (dy2 >= bi) continue;
                for (int j2 = 0; j2 < W_; ++j2) {
                    if (mask[mrow + (i2 << 8) + j2]) {
                        int dx = j2 - j;
                        int dd = dy2 + dx * dx;
                        if (dd < bi) bi = dd;
                    }
                }
            }
            best = (bi < (1 << 28)) ? (float)bi : 1.0e12f;  // empty -> w=0
        }

        float w = __expf(-sqrtf(best) * INV_BETA);

        // 2-class CE = softplus(-(p_t - p_other))
        float z  = (initOwn[r] == 0.0f) ? (pf1[r] - pf0[r]) : (pf0[r] - pf1[r]);
        float ce = __logf(1.0f + __expf(-z));
        vsum += ce * (1.0f + ALPHA * w);
    }

    // block reduction (512 threads, 8 waves) -> one partial
    for (int off = 32; off > 0; off >>= 1)
        vsum += __shfl_down(vsum, off, 64);
    const int lane = tid & 63;
    const int wid  = tid >> 6;
    if (lane == 0) s_part[wid] = vsum;
    __syncthreads();
    if (tid == 0) {
        float ssum = 0.0f;
        #pragma unroll
        for (int k = 0; k < 8; ++k) ssum += s_part[k];
        partials[g] = ssum;
    }
}

// ---------------------------------------------------------------------------
// Final deterministic reduction of NBLK partials -> mean.
// ---------------------------------------------------------------------------
__global__ void final_reduce_kernel(const float* __restrict__ partials,
                                    float* __restrict__ out,
                                    float scale) {
    __shared__ float s_part[4];
    const int t = threadIdx.x;           // 256 threads
    float v = partials[t];
    for (int off = 32; off > 0; off >>= 1)
        v += __shfl_down(v, off, 64);
    if ((t & 63) == 0) s_part[t >> 6] = v;
    __syncthreads();
    if (t == 0)
        out[0] = (s_part[0] + s_part[1] + s_part[2] + s_part[3]) * scale;
}

extern "C" void kernel_launch(void* const* d_in, const int* in_sizes, int n_in,
                              void* d_out, int out_size, void* d_ws, size_t ws_size,
                              hipStream_t stream) {
    const float* pred = (const float*)d_in[0];          // [B,2,H,W] f32
    const int*   mask = (const int*)d_in[1];            // [B,H,W] i32
    float* out = (float*)d_out;

    float* partials = (float*)d_ws;                     // NBLK floats

    fused_loss_kernel<<<NBLK, 512, 0, stream>>>(pred, mask, partials);
    final_reduce_kernel<<<1, NBLK, 0, stream>>>(partials, out,
                                                1.0f / (float)(B_ * H_ * W_));
}

// Round 10
// 14.257 us; speedup vs baseline: 1.2020x; 1.2020x over previous
//
#include <hip/hip_runtime.h>
#include <hip/hip_bf16.h>

#define INF_SENT 1.0e6f
#define ALPHA 1.0f
#define INV_BETA 0.5f

#define B_ 16
#define H_ 256
#define W_ 256
#define SEG 8
#define NSEG 32           // H_/SEG
#define NBLK (B_ * NSEG)  // 512 blocks
#define RPAD 8            // vertical halo rows each side

// ---------------------------------------------------------------------------
// Fused self-sufficient kernel (R8 structure, RPAD=8): per block (b, 8-row
// segment), 256 threads = one column each.
//   1) vertical two-scan over segment +/- RPAD halo (exact when dist <= RPAD)
//   2) LDS row tiles -> adaptive exact horizontal min (early exit d^2>=best)
//   3) best >= (RPAD+1)^2 => exact global 2D search (needs an empty radius-9
//      disk; P~2^-254 at p=0.5 — never taken, exactness for any input)
//   4) CE + weight -> one partial per block. No cross-block deps/atomics.
//
// Exactness: columns with true vertical dist > RPAD have windowed g ~ 1e6,
// and their true contribution >= (RPAD+1)^2; if best < (RPAD+1)^2 all
// contributing columns were exact, so best is the true min.
// Early-exit: skipped terms fl(g2[k]+d2) >= d2 >= best (RN monotone).
// ---------------------------------------------------------------------------
__global__ void fused_loss_kernel(const float* __restrict__ pred,
                                  const int* __restrict__ mask,
                                  float* __restrict__ partials) {
    const int bs = blockIdx.x;
    const int b  = bs >> 5;
    const int s  = bs & (NSEG - 1);
    const int j  = threadIdx.x;
    const int i0 = s * SEG;

    __shared__ float s_g2[SEG][W_];
    __shared__ float s_part[4];

    // prefetch logits early; latency hides under the scans
    float pf0[SEG], pf1[SEG];
    const int pb = ((b * 2) << 16) + (i0 << 8) + j;
    #pragma unroll
    for (int r = 0; r < SEG; ++r) {
        pf0[r] = pred[pb + (r << 8)];
        pf1[r] = pred[pb + (r << 8) + H_ * W_];
    }

    const int mb = (b << 16) + j;

    // forward scan: rows i0-RPAD .. i0+SEG-1 (out-of-image -> INF)
    float F[SEG], initOwn[SEG];
    float c = INF_SENT;
    #pragma unroll
    for (int t = 0; t < RPAD + SEG; ++t) {
        const int row = i0 - RPAD + t;            // uniform across block
        float init = INF_SENT;
        if (row >= 0) init = mask[mb + (row << 8)] ? 0.0f : INF_SENT;
        c = fminf(c + 1.0f, init);
        if (t >= RPAD) { F[t - RPAD] = c; initOwn[t - RPAD] = init; }
    }
    // backward scan: rows i0+SEG+RPAD-1 .. i0
    c = INF_SENT;
    #pragma unroll
    for (int t = RPAD + SEG + RPAD - 1; t >= RPAD; --t) {
        const int row = i0 - RPAD + t;
        float init;
        if (t < RPAD + SEG) init = initOwn[t - RPAD];
        else { init = INF_SENT; if (row < H_) init = mask[mb + (row << 8)] ? 0.0f : INF_SENT; }
        c = fminf(c + 1.0f, init);
        if (t < RPAD + SEG) {
            float g = fminf(F[t - RPAD], c);
            s_g2[t - RPAD][j] = g * g;
        }
    }
    __syncthreads();

    // per-row adaptive exact horizontal min + CE + weight
    float vsum = 0.0f;
    #pragma unroll
    for (int r = 0; r < SEG; ++r) {
        float best = s_g2[r][j];
        for (int d = 1; d < W_; ++d) {
            float d2 = (float)(d * d);
            if (d2 >= best) break;
            int kl = j - d, kr = j + d;
            if (kl >= 0)  best = fminf(best, s_g2[r][kl] + d2);
            if (kr < W_)  best = fminf(best, s_g2[r][kr] + d2);
        }

        // window-truncation guard: exact global 2D search (never taken here)
        if (best >= (float)((RPAD + 1) * (RPAD + 1))) {
            const int ii = i0 + r;
            const int mrow = (b << 16);
            int bi = 1 << 28;
            for (int i2 = 0; i2 < H_; ++i2) {
                int dy = i2 - ii, dy2 = dy * dy;
                if (dy2 >= bi) continue;
                for (int j2 = 0; j2 < W_; ++j2) {
                    if (mask[mrow + (i2 << 8) + j2]) {
                        int dx = j2 - j;
                        int dd = dy2 + dx * dx;
                        if (dd < bi) bi = dd;
                    }
                }
            }
            best = (bi < (1 << 28)) ? (float)bi : 1.0e12f;  // empty -> w=0
        }

        float w = __expf(-sqrtf(best) * INV_BETA);

        // 2-class CE = softplus(-(p_t - p_other))
        float z  = (initOwn[r] == 0.0f) ? (pf1[r] - pf0[r]) : (pf0[r] - pf1[r]);
        float ce = __logf(1.0f + __expf(-z));
        vsum += ce * (1.0f + ALPHA * w);
    }

    // block reduction -> one partial
    for (int off = 32; off > 0; off >>= 1)
        vsum += __shfl_down(vsum, off, 64);
    const int lane = j & 63;
    const int wid  = j >> 6;
    if (lane == 0) s_part[wid] = vsum;
    __syncthreads();
    if (j == 0)
        partials[bs] = s_part[0] + s_part[1] + s_part[2] + s_part[3];
}

// ---------------------------------------------------------------------------
// Final deterministic reduction of NBLK partials -> mean.
// ---------------------------------------------------------------------------
__global__ void final_reduce_kernel(const float* __restrict__ partials,
                                    float* __restrict__ out,
                                    float scale) {
    __shared__ float s_part[8];
    const int t = threadIdx.x;           // 512 threads
    float v = partials[t];
    for (int off = 32; off > 0; off >>= 1)
        v += __shfl_down(v, off, 64);
    if ((t & 63) == 0) s_part[t >> 6] = v;
    __syncthreads();
    if (t == 0) {
        float ssum = 0.0f;
        #pragma unroll
        for (int k = 0; k < 8; ++k) ssum += s_part[k];
        out[0] = ssum * scale;
    }
}

extern "C" void kernel_launch(void* const* d_in, const int* in_sizes, int n_in,
                              void* d_out, int out_size, void* d_ws, size_t ws_size,
                              hipStream_t stream) {
    const float* pred = (const float*)d_in[0];          // [B,2,H,W] f32
    const int*   mask = (const int*)d_in[1];            // [B,H,W] i32
    float* out = (float*)d_out;

    float* partials = (float*)d_ws;                     // NBLK floats

    fused_loss_kernel<<<NBLK, W_, 0, stream>>>(pred, mask, partials);
    final_reduce_kernel<<<1, NBLK, 0, stream>>>(partials, out,
                                                1.0f / (float)(B_ * H_ * W_));
}

// Round 11
// 13.321 us; speedup vs baseline: 1.2866x; 1.0703x over previous
//
#include <hip/hip_runtime.h>
#include <hip/hip_bf16.h>

#define INF_SENT 1.0e6f
#define ALPHA 1.0f
#define INV_BETA 0.5f

#define B_ 16
#define H_ 256
#define W_ 256
#define SEG 8
#define NSEG 32           // H_/SEG
#define NBLK (B_ * NSEG)  // 512 blocks
#define RPAD 4            // vertical halo rows each side

// ---------------------------------------------------------------------------
// Fused self-sufficient kernel (R10 structure, RPAD=4): per block (b, 8-row
// segment), 256 threads = one column each.
//   1) vertical two-scan over segment +/- RPAD halo (exact when dist <= RPAD)
//   2) LDS row tiles -> adaptive exact horizontal min (early exit d^2>=best)
//   3) best >= (RPAD+1)^2 => exact global 2D search (needs an empty radius-5
//      disk; P~2^-78 per pixel at p=0.5 — never taken; exact for any input)
//   4) CE + weight -> one partial per block. No cross-block deps/atomics.
//
// Exactness: columns with true vertical dist > RPAD have windowed g ~ 1e6,
// and their true contribution >= (RPAD+1)^2; if best < (RPAD+1)^2 all
// contributing columns were exact, so best is the true min.
// Early-exit: skipped terms fl(g2[k]+d2) >= d2 >= best (RN monotone).
// ---------------------------------------------------------------------------
__global__ void fused_loss_kernel(const float* __restrict__ pred,
                                  const int* __restrict__ mask,
                                  float* __restrict__ partials) {
    const int bs = blockIdx.x;
    const int b  = bs >> 5;
    const int s  = bs & (NSEG - 1);
    const int j  = threadIdx.x;
    const int i0 = s * SEG;

    __shared__ float s_g2[SEG][W_];
    __shared__ float s_part[4];

    // prefetch logits early; latency hides under the scans
    float pf0[SEG], pf1[SEG];
    const int pb = ((b * 2) << 16) + (i0 << 8) + j;
    #pragma unroll
    for (int r = 0; r < SEG; ++r) {
        pf0[r] = pred[pb + (r << 8)];
        pf1[r] = pred[pb + (r << 8) + H_ * W_];
    }

    const int mb = (b << 16) + j;

    // forward scan: rows i0-RPAD .. i0+SEG-1 (out-of-image -> INF)
    float F[SEG], initOwn[SEG];
    float c = INF_SENT;
    #pragma unroll
    for (int t = 0; t < RPAD + SEG; ++t) {
        const int row = i0 - RPAD + t;            // uniform across block
        float init = INF_SENT;
        if (row >= 0) init = mask[mb + (row << 8)] ? 0.0f : INF_SENT;
        c = fminf(c + 1.0f, init);
        if (t >= RPAD) { F[t - RPAD] = c; initOwn[t - RPAD] = init; }
    }
    // backward scan: rows i0+SEG+RPAD-1 .. i0
    c = INF_SENT;
    #pragma unroll
    for (int t = RPAD + SEG + RPAD - 1; t >= RPAD; --t) {
        const int row = i0 - RPAD + t;
        float init;
        if (t < RPAD + SEG) init = initOwn[t - RPAD];
        else { init = INF_SENT; if (row < H_) init = mask[mb + (row << 8)] ? 0.0f : INF_SENT; }
        c = fminf(c + 1.0f, init);
        if (t < RPAD + SEG) {
            float g = fminf(F[t - RPAD], c);
            s_g2[t - RPAD][j] = g * g;
        }
    }
    __syncthreads();

    // per-row adaptive exact horizontal min + CE + weight
    float vsum = 0.0f;
    #pragma unroll
    for (int r = 0; r < SEG; ++r) {
        float best = s_g2[r][j];
        for (int d = 1; d < W_; ++d) {
            float d2 = (float)(d * d);
            if (d2 >= best) break;
            int kl = j - d, kr = j + d;
            if (kl >= 0)  best = fminf(best, s_g2[r][kl] + d2);
            if (kr < W_)  best = fminf(best, s_g2[r][kr] + d2);
        }

        // window-truncation guard: exact global 2D search (never taken here)
        if (best >= (float)((RPAD + 1) * (RPAD + 1))) {
            const int ii = i0 + r;
            const int mrow = (b << 16);
            int bi = 1 << 28;
            for (int i2 = 0; i2 < H_; ++i2) {
                int dy = i2 - ii, dy2 = dy * dy;
                if (dy2 >= bi) continue;
                for (int j2 = 0; j2 < W_; ++j2) {
                    if (mask[mrow + (i2 << 8) + j2]) {
                        int dx = j2 - j;
                        int dd = dy2 + dx * dx;
                        if (dd < bi) bi = dd;
                    }
                }
            }
            best = (bi < (1 << 28)) ? (float)bi : 1.0e12f;  // empty -> w=0
        }

        float w = __expf(-sqrtf(best) * INV_BETA);

        // 2-class CE = softplus(-(p_t - p_other))
        float z  = (initOwn[r] == 0.0f) ? (pf1[r] - pf0[r]) : (pf0[r] - pf1[r]);
        float ce = __logf(1.0f + __expf(-z));
        vsum += ce * (1.0f + ALPHA * w);
    }

    // block reduction -> one partial
    for (int off = 32; off > 0; off >>= 1)
        vsum += __shfl_down(vsum, off, 64);
    const int lane = j & 63;
    const int wid  = j >> 6;
    if (lane == 0) s_part[wid] = vsum;
    __syncthreads();
    if (j == 0)
        partials[bs] = s_part[0] + s_part[1] + s_part[2] + s_part[3];
}

// ---------------------------------------------------------------------------
// Final deterministic reduction of NBLK partials -> mean.
// ---------------------------------------------------------------------------
__global__ void final_reduce_kernel(const float* __restrict__ partials,
                                    float* __restrict__ out,
                                    float scale) {
    __shared__ float s_part[8];
    const int t = threadIdx.x;           // 512 threads
    float v = partials[t];
    for (int off = 32; off > 0; off >>= 1)
        v += __shfl_down(v, off, 64);
    if ((t & 63) == 0) s_part[t >> 6] = v;
    __syncthreads();
    if (t == 0) {
        float ssum = 0.0f;
        #pragma unroll
        for (int k = 0; k < 8; ++k) ssum += s_part[k];
        out[0] = ssum * scale;
    }
}

extern "C" void kernel_launch(void* const* d_in, const int* in_sizes, int n_in,
                              void* d_out, int out_size, void* d_ws, size_t ws_size,
                              hipStream_t stream) {
    const float* pred = (const float*)d_in[0];          // [B,2,H,W] f32
    const int*   mask = (const int*)d_in[1];            // [B,H,W] i32
    float* out = (float*)d_out;

    float* partials = (float*)d_ws;                     // NBLK floats

    fused_loss_kernel<<<NBLK, W_, 0, stream>>>(pred, mask, partials);
    final_reduce_kernel<<<1, NBLK, 0, stream>>>(partials, out,
                                                1.0f / (float)(B_ * H_ * W_));
}

// Round 12
// 13.138 us; speedup vs baseline: 1.3044x; 1.0139x over previous
//
#include <hip/hip_runtime.h>
#include <hip/hip_bf16.h>

#define INF_SENT 1.0e6f
#define ALPHA 1.0f
#define INV_BETA 0.5f

#define B_ 16
#define H_ 256
#define W_ 256
#define SEG 8
#define NSEG 32           // H_/SEG
#define NBLK (B_ * NSEG)  // 512 blocks
#define RPAD 3            // vertical halo rows each side

// ---------------------------------------------------------------------------
// Fused self-sufficient kernel (R11 structure, RPAD=3): per block (b, 8-row
// segment), 256 threads = one column each.
//   1) vertical two-scan over segment +/- RPAD halo (exact when dist <= RPAD)
//   2) LDS row tiles -> adaptive exact horizontal min (early exit d^2>=best)
//   3) best >= (RPAD+1)^2 => exact global 2D search (needs an empty radius-4
//      disk; P~2^-45 per pixel at p=0.5 — never taken; exact for any input)
//   4) CE + weight -> one partial per block. No cross-block deps/atomics.
//
// Exactness: columns with true vertical dist > RPAD have windowed g ~ 1e6,
// and their true contribution >= (RPAD+1)^2; if best < (RPAD+1)^2 all
// contributing columns were exact, so best is the true min.
// Early-exit: skipped terms fl(g2[k]+d2) >= d2 >= best (RN monotone).
// ---------------------------------------------------------------------------
__global__ void fused_loss_kernel(const float* __restrict__ pred,
                                  const int* __restrict__ mask,
                                  float* __restrict__ partials) {
    const int bs = blockIdx.x;
    const int b  = bs >> 5;
    const int s  = bs & (NSEG - 1);
    const int j  = threadIdx.x;
    const int i0 = s * SEG;

    __shared__ float s_g2[SEG][W_];
    __shared__ float s_part[4];

    const int mb = (b << 16) + j;

    // mask loads first: they gate the scan (critical path)
    float initHalo[2 * RPAD + SEG];
    #pragma unroll
    for (int t = 0; t < 2 * RPAD + SEG; ++t) {
        const int row = i0 - RPAD + t;
        float init = INF_SENT;
        if (row >= 0 && row < H_) init = mask[mb + (row << 8)] ? 0.0f : INF_SENT;
        initHalo[t] = init;
    }

    // prefetch logits; consumed only after the barrier, latency hides
    float pf0[SEG], pf1[SEG];
    const int pb = ((b * 2) << 16) + (i0 << 8) + j;
    #pragma unroll
    for (int r = 0; r < SEG; ++r) {
        pf0[r] = pred[pb + (r << 8)];
        pf1[r] = pred[pb + (r << 8) + H_ * W_];
    }

    // forward scan over rows i0-RPAD .. i0+SEG-1
    float F[SEG];
    float c = INF_SENT;
    #pragma unroll
    for (int t = 0; t < RPAD + SEG; ++t) {
        c = fminf(c + 1.0f, initHalo[t]);
        if (t >= RPAD) F[t - RPAD] = c;
    }
    // backward scan over rows i0+SEG+RPAD-1 .. i0
    c = INF_SENT;
    #pragma unroll
    for (int t = RPAD + SEG + RPAD - 1; t >= RPAD; --t) {
        c = fminf(c + 1.0f, initHalo[t]);
        if (t < RPAD + SEG) {
            float g = fminf(F[t - RPAD], c);
            s_g2[t - RPAD][j] = g * g;
        }
    }
    __syncthreads();

    // per-row adaptive exact horizontal min + CE + weight
    float vsum = 0.0f;
    #pragma unroll
    for (int r = 0; r < SEG; ++r) {
        float best = s_g2[r][j];
        for (int d = 1; d < W_; ++d) {
            float d2 = (float)(d * d);
            if (d2 >= best) break;
            int kl = j - d, kr = j + d;
            if (kl >= 0)  best = fminf(best, s_g2[r][kl] + d2);
            if (kr < W_)  best = fminf(best, s_g2[r][kr] + d2);
        }

        // window-truncation guard: exact global 2D search (never taken here)
        if (best >= (float)((RPAD + 1) * (RPAD + 1))) {
            const int ii = i0 + r;
            const int mrow = (b << 16);
            int bi = 1 << 28;
            for (int i2 = 0; i2 < H_; ++i2) {
                int dy = i2 - ii, dy2 = dy * dy;
                if (dy2 >= bi) continue;
                for (int j2 = 0; j2 < W_; ++j2) {
                    if (mask[mrow + (i2 << 8) + j2]) {
                        int dx = j2 - j;
                        int dd = dy2 + dx * dx;
                        if (dd < bi) bi = dd;
                    }
                }
            }
            best = (bi < (1 << 28)) ? (float)bi : 1.0e12f;  // empty -> w=0
        }

        float w = __expf(-sqrtf(best) * INV_BETA);

        // 2-class CE = softplus(-(p_t - p_other))
        float z  = (initHalo[RPAD + r] == 0.0f) ? (pf1[r] - pf0[r])
                                                : (pf0[r] - pf1[r]);
        float ce = __logf(1.0f + __expf(-z));
        vsum += ce * (1.0f + ALPHA * w);
    }

    // block reduction -> one partial
    for (int off = 32; off > 0; off >>= 1)
        vsum += __shfl_down(vsum, off, 64);
    const int lane = j & 63;
    const int wid  = j >> 6;
    if (lane == 0) s_part[wid] = vsum;
    __syncthreads();
    if (j == 0)
        partials[bs] = s_part[0] + s_part[1] + s_part[2] + s_part[3];
}

// ---------------------------------------------------------------------------
// Final deterministic reduction of NBLK partials -> mean. 256 threads,
// each folds two partials first (4 waves, one LDS round).
// ---------------------------------------------------------------------------
__global__ void final_reduce_kernel(const float* __restrict__ partials,
                                    float* __restrict__ out,
                                    float scale) {
    __shared__ float s_part[4];
    const int t = threadIdx.x;           // 256 threads
    float v = partials[t] + partials[t + 256];
    for (int off = 32; off > 0; off >>= 1)
        v += __shfl_down(v, off, 64);
    if ((t & 63) == 0) s_part[t >> 6] = v;
    __syncthreads();
    if (t == 0)
        out[0] = (s_part[0] + s_part[1] + s_part[2] + s_part[3]) * scale;
}

extern "C" void kernel_launch(void* const* d_in, const int* in_sizes, int n_in,
                              void* d_out, int out_size, void* d_ws, size_t ws_size,
                              hipStream_t stream) {
    const float* pred = (const float*)d_in[0];          // [B,2,H,W] f32
    const int*   mask = (const int*)d_in[1];            // [B,H,W] i32
    float* out = (float*)d_out;

    float* partials = (float*)d_ws;                     // NBLK floats

    fused_loss_kernel<<<NBLK, W_, 0, stream>>>(pred, mask, partials);
    final_reduce_kernel<<<1, 256, 0, stream>>>(partials, out,
                                               1.0f / (float)(B_ * H_ * W_));
}